// Round 1
// baseline (4715.756 us; speedup 1.0000x reference)
//
#include <hip/hip_runtime.h>
#include <hip/hip_bf16.h>
#include <math.h>

// Profile-HMM forward (scaled) for MsaHmmLayer.
// M=4 models, B=64 batch, L=512 steps, Q=512 states, S=26 alphabet.
//
// Design (round 1):
//  - preproc: softmax(pi), softmax(Bem), softmax(A)->At[m][p][q] bf16 (transposed
//    so MFMA B-fragments are single b128 loads), E[m][t][b][q] bf16 = inputs @ Bem^T.
//  - scan: persistent kernel, 64 blocks = 16 clusters x 4 WGs. Cluster = (m, group
//    of 16 batches). Each WG owns a 128-column slice of A[m] held entirely in VGPRs
//    as MFMA B-frags (breg, 128 VGPRs/wave). Per step: stage alpha from global
//    exchange buffer (scaled by 1/s_{t-1}), 16x16x32 bf16 MFMA over K=512, multiply
//    e_t, partial sums + alpha slice to global, device-scope flag barrier per cluster.
//    loglik = sum log s_t accumulated by WG j==0 of each cluster.

#define MM 4
#define BB 64
#define LL 512
#define QQ 512
#define SS 26
#define NCLU 16

typedef short bf16x8 __attribute__((ext_vector_type(8)));
typedef float f32x4 __attribute__((ext_vector_type(4)));

__device__ __forceinline__ float bf2f(unsigned short u) {
    return __uint_as_float(((unsigned)u) << 16);
}
__device__ __forceinline__ unsigned short f2bf(float f) {
    unsigned u = __float_as_uint(f);
    u = u + 0x7FFFu + ((u >> 16) & 1u);   // RNE
    return (unsigned short)(u >> 16);
}

// ---------------- preproc ----------------

// grid MM*(QQ+1), block 64. r<QQ: Bem row softmax over S; r==QQ: pi softmax over Q.
__global__ void prep_small(const float* __restrict__ il, const float* __restrict__ em,
                           float* __restrict__ pi, float* __restrict__ Bem) {
    int blk = blockIdx.x;
    int m = blk / (QQ + 1);
    int r = blk % (QQ + 1);
    int lane = threadIdx.x;
    if (r < QQ) {
        float x = (lane < SS) ? em[((size_t)m * QQ + r) * SS + lane] : -1e30f;
        float mx = x;
        #pragma unroll
        for (int o = 1; o < 64; o <<= 1) mx = fmaxf(mx, __shfl_xor(mx, o));
        float e = (lane < SS) ? __expf(x - mx) : 0.f;
        float s = e;
        #pragma unroll
        for (int o = 1; o < 64; o <<= 1) s += __shfl_xor(s, o);
        if (lane < SS) Bem[((size_t)m * QQ + r) * SS + lane] = e / s;
    } else {
        float v[8];
        float mx = -1e30f;
        #pragma unroll
        for (int k = 0; k < 8; ++k) { v[k] = il[m * QQ + k * 64 + lane]; mx = fmaxf(mx, v[k]); }
        #pragma unroll
        for (int o = 1; o < 64; o <<= 1) mx = fmaxf(mx, __shfl_xor(mx, o));
        float s = 0.f;
        #pragma unroll
        for (int k = 0; k < 8; ++k) { v[k] = __expf(v[k] - mx); s += v[k]; }
        #pragma unroll
        for (int o = 1; o < 64; o <<= 1) s += __shfl_xor(s, o);
        #pragma unroll
        for (int k = 0; k < 8; ++k) pi[m * QQ + k * 64 + lane] = v[k] / s;
    }
}

// grid MM*QQ, block 64: per A row (m,q): Lrow = max + log(sum exp).
__global__ void prep_arow(const float* __restrict__ Al, float* __restrict__ Lrow) {
    int row = blockIdx.x;
    int lane = threadIdx.x;
    const float* p = Al + (size_t)row * QQ;
    float v[8];
    float mx = -1e30f;
    #pragma unroll
    for (int k = 0; k < 8; ++k) { v[k] = p[k * 64 + lane]; mx = fmaxf(mx, v[k]); }
    #pragma unroll
    for (int o = 1; o < 64; o <<= 1) mx = fmaxf(mx, __shfl_xor(mx, o));
    float s = 0.f;
    #pragma unroll
    for (int k = 0; k < 8; ++k) s += __expf(v[k] - mx);
    #pragma unroll
    for (int o = 1; o < 64; o <<= 1) s += __shfl_xor(s, o);
    if (lane == 0) Lrow[row] = mx + __logf(s);
}

// grid MM*8*8 (m, qt, pt), block 256: At[m][p][q] = softmax_p(A_logits[m][q][:])[p], bf16.
__global__ void prep_at(const float* __restrict__ Al, const float* __restrict__ Lrow,
                        unsigned short* __restrict__ At) {
    int bid = blockIdx.x;
    int m = bid >> 6, qt = (bid >> 3) & 7, pt = bid & 7;
    __shared__ unsigned short tile[64 * 68];
    int cc = threadIdx.x & 63, rg = threadIdx.x >> 6;
    #pragma unroll
    for (int g = 0; g < 16; ++g) {
        int r = g * 4 + rg;
        int q = qt * 64 + r;
        float x = Al[((size_t)m * QQ + q) * QQ + pt * 64 + cc];
        tile[r * 68 + cc] = f2bf(__expf(x - Lrow[m * QQ + q]));
    }
    __syncthreads();
    #pragma unroll
    for (int g = 0; g < 16; ++g) {
        int pr = g * 4 + rg;
        At[((size_t)m * QQ + pt * 64 + pr) * QQ + qt * 64 + cc] = tile[cc * 68 + pr];
    }
}

// grid MM*BB*(LL/16), block 256: E[m][t][b][q] bf16 = sum_s inputs[m,b,t,s]*Bem[m,q,s].
__global__ void prep_e(const float* __restrict__ inp, const float* __restrict__ Bem,
                       unsigned short* __restrict__ E) {
    int bid = blockIdx.x;
    int lb = bid & 31;
    int mb = bid >> 5;
    int b = mb & 63, m = mb >> 6;
    __shared__ float bem[QQ * SS];
    __shared__ float intile[16 * SS];
    for (int i = threadIdx.x; i < QQ * SS; i += 256) bem[i] = Bem[(size_t)m * QQ * SS + i];
    for (int i = threadIdx.x; i < 16 * SS; i += 256)
        intile[i] = inp[(((size_t)(m * BB + b)) * LL + lb * 16) * SS + i];
    __syncthreads();
    for (int l = 0; l < 16; ++l) {
        int t = lb * 16 + l;
        #pragma unroll
        for (int rep = 0; rep < 2; ++rep) {
            int q = rep * 256 + threadIdx.x;
            float a = 0.f;
            #pragma unroll
            for (int j = 0; j < SS; ++j) a += intile[l * SS + j] * bem[q * SS + j];
            E[(((size_t)m * LL + t) * BB + b) * QQ + q] = f2bf(a);
        }
    }
}

// ---------------- scan ----------------

__device__ __forceinline__ void step_tail(
    float v[2][4], int P, int c, int j, int wv, int n16, int quad, int pslice,
    unsigned short* __restrict__ ax, float* __restrict__ psum,
    unsigned int* __restrict__ flags, float* psl, int tid) {
    // write unnormalized alpha_t slice (bf16) to exchange buffer
    unsigned short* axb = ax + ((size_t)(P * NCLU + c)) * 16 * QQ;
    #pragma unroll
    for (int h = 0; h < 2; ++h) {
        int p = pslice + (wv * 2 + h) * 16 + n16;
        #pragma unroll
        for (int i = 0; i < 4; ++i) {
            int s = quad * 4 + i;
            axb[(size_t)s * QQ + p] = f2bf(v[h][i]);
        }
    }
    // partial sums over this WG's 128 p, per stream
    #pragma unroll
    for (int i = 0; i < 4; ++i) {
        float ps = v[0][i] + v[1][i];
        ps += __shfl_xor(ps, 1);
        ps += __shfl_xor(ps, 2);
        ps += __shfl_xor(ps, 4);
        ps += __shfl_xor(ps, 8);
        if (n16 == 0) atomicAdd(&psl[quad * 4 + i], ps);
    }
    __syncthreads();
    if (tid < 16)
        psum[((size_t)(P * NCLU + c) * 4 + j) * 16 + tid] = psl[tid];
    if (tid == 0) {
        __threadfence();  // agent release: drain + L2 writeback
        __hip_atomic_fetch_add(&flags[P * NCLU + c], 1u, __ATOMIC_RELEASE,
                               __HIP_MEMORY_SCOPE_AGENT);
    }
}

__launch_bounds__(256, 1)
__global__ void hmm_scan(const unsigned short* __restrict__ E,
                         const unsigned short* __restrict__ At,
                         const float* __restrict__ pi,
                         unsigned short* __restrict__ ax,   // [2][16][16][512] bf16
                         float* __restrict__ psum,          // [2][16][4][16]
                         unsigned int* __restrict__ flags,  // [2][16]
                         float* __restrict__ out) {
    // cluster c = blockIdx & 15 so the 4 WGs of a cluster are 16 apart in blockIdx
    // (likely same XCD under %8 round-robin; correctness is agent-scope regardless).
    const int c = blockIdx.x & 15;
    const int j = blockIdx.x >> 4;
    const int m = c >> 2;
    const int bg = c & 3;
    const int tid = threadIdx.x;
    const int lane = tid & 63;
    const int wv = tid >> 6;
    const int n16 = lane & 15;
    const int quad = lane >> 4;
    const int pslice = j * 128;

    __shared__ unsigned short albuf[16 * 520];  // [s][q] bf16, stride 520 (16B-aligned, ~2-way banks)
    __shared__ float psl[16];

    // persistent B fragments: this wave's 32 columns of A[m], all K. 128 VGPRs.
    bf16x8 breg0[16], breg1[16];
    {
        const unsigned short* bA = At + (size_t)m * QQ * QQ;
        int p0 = pslice + (wv * 2 + 0) * 16 + n16;
        int p1 = pslice + (wv * 2 + 1) * 16 + n16;
        #pragma unroll
        for (int kt = 0; kt < 16; ++kt) {
            breg0[kt] = *(const bf16x8*)(bA + (size_t)p0 * QQ + kt * 32 + quad * 8);
            breg1[kt] = *(const bf16x8*)(bA + (size_t)p1 * QQ + kt * 32 + quad * 8);
        }
    }

    if (tid < 16) psl[tid] = 0.f;
    __syncthreads();

    float ll = 0.f;

    // ---- t = 0: alpha0 = pi * e0 (unnormalized; s0 via partial sums)
    {
        float v[2][4];
        #pragma unroll
        for (int h = 0; h < 2; ++h) {
            int p = pslice + (wv * 2 + h) * 16 + n16;
            float pv = pi[m * QQ + p];
            #pragma unroll
            for (int i = 0; i < 4; ++i) {
                int s = quad * 4 + i;
                int b = bg * 16 + s;
                unsigned short eu = E[(((size_t)m * LL + 0) * BB + b) * QQ + p];
                v[h][i] = pv * bf2f(eu);
            }
        }
        step_tail(v, 0, c, j, wv, n16, quad, pslice, ax, psum, flags, psl, tid);
    }

    for (int t = 1; t < LL; ++t) {
        const int P = t & 1;
        const int Pb = P ^ 1;
        if (tid == 0) {
            const unsigned tgt = 4u * ((((unsigned)t - 1u) >> 1) + 1u);
            while (__hip_atomic_load(&flags[Pb * NCLU + c], __ATOMIC_RELAXED,
                                     __HIP_MEMORY_SCOPE_AGENT) < tgt)
                __builtin_amdgcn_s_sleep(1);
            __threadfence();  // agent acquire: invalidate stale cache
        }
        if (tid < 16) psl[tid] = 0.f;
        __syncthreads();

        // stage alpha_{t-1}: scale by 1/s_{t-1} and write to LDS
        {
            int s = tid & 15;
            int q0 = (tid >> 4) * 32;
            const float* pp = psum + ((size_t)(Pb * NCLU + c)) * 64;
            float sp = pp[s] + pp[16 + s] + pp[32 + s] + pp[48 + s];
            float inv = 1.0f / sp;
            const unsigned short* src = ax + (((size_t)(Pb * NCLU + c)) * 16 + s) * QQ + q0;
            unsigned short* dst = albuf + s * 520 + q0;
            #pragma unroll
            for (int kb = 0; kb < 4; ++kb) {
                bf16x8 vv = *(const bf16x8*)(src + kb * 8);
                bf16x8 ov;
                #pragma unroll
                for (int e = 0; e < 8; ++e)
                    ov[e] = (short)f2bf(bf2f((unsigned short)vv[e]) * inv);
                *(bf16x8*)(dst + kb * 8) = ov;
            }
            if (j == 0 && tid < 16) {  // loglik accumulation: log s_{t-1}
                float sv = pp[tid] + pp[16 + tid] + pp[32 + tid] + pp[48 + tid];
                ll += __logf(sv);
            }
        }
        __syncthreads();

        // prefetch e_t for this wave's (s,p) cells
        unsigned short eu[2][4];
        #pragma unroll
        for (int h = 0; h < 2; ++h) {
            int p = pslice + (wv * 2 + h) * 16 + n16;
            #pragma unroll
            for (int i = 0; i < 4; ++i) {
                int s = quad * 4 + i;
                int b = bg * 16 + s;
                eu[h][i] = E[(((size_t)m * LL + t) * BB + b) * QQ + p];
            }
        }

        // r = alpha @ A : 32 MFMA, 4 independent acc chains
        f32x4 a00 = {0.f, 0.f, 0.f, 0.f}, a01 = {0.f, 0.f, 0.f, 0.f};
        f32x4 a10 = {0.f, 0.f, 0.f, 0.f}, a11 = {0.f, 0.f, 0.f, 0.f};
        #pragma unroll
        for (int kt = 0; kt < 16; ++kt) {
            bf16x8 af = *(const bf16x8*)(albuf + n16 * 520 + kt * 32 + quad * 8);
            if (kt & 1) {
                a01 = __builtin_amdgcn_mfma_f32_16x16x32_bf16(af, breg0[kt], a01, 0, 0, 0);
                a11 = __builtin_amdgcn_mfma_f32_16x16x32_bf16(af, breg1[kt], a11, 0, 0, 0);
            } else {
                a00 = __builtin_amdgcn_mfma_f32_16x16x32_bf16(af, breg0[kt], a00, 0, 0, 0);
                a10 = __builtin_amdgcn_mfma_f32_16x16x32_bf16(af, breg1[kt], a10, 0, 0, 0);
            }
        }
        float v[2][4];
        #pragma unroll
        for (int i = 0; i < 4; ++i) {
            v[0][i] = (a00[i] + a01[i]) * bf2f(eu[0][i]);
            v[1][i] = (a10[i] + a11[i]) * bf2f(eu[1][i]);
        }
        step_tail(v, P, c, j, wv, n16, quad, pslice, ax, psum, flags, psl, tid);
    }

    // final: wait for step 511 partials, add log s_511, write output
    if (tid == 0) {
        while (__hip_atomic_load(&flags[1 * NCLU + c], __ATOMIC_RELAXED,
                                 __HIP_MEMORY_SCOPE_AGENT) < 1024u)
            __builtin_amdgcn_s_sleep(1);
        __threadfence();
    }
    __syncthreads();
    if (j == 0 && tid < 16) {
        const float* pp = psum + ((size_t)(1 * NCLU + c)) * 64;
        float sv = pp[tid] + pp[16 + tid] + pp[32 + tid] + pp[48 + tid];
        ll += __logf(sv);
        out[m * BB + bg * 16 + tid] = ll;
    }
}

// ---------------- host ----------------

extern "C" void kernel_launch(void* const* d_in, const int* in_sizes, int n_in,
                              void* d_out, int out_size, void* d_ws, size_t ws_size,
                              hipStream_t stream) {
    const float* inputs = (const float*)d_in[0];
    const float* A_logits = (const float*)d_in[1];
    const float* init_logits = (const float*)d_in[2];
    const float* em_logits = (const float*)d_in[3];
    float* out = (float*)d_out;

    char* ws = (char*)d_ws;
    size_t off = 0;
    unsigned short* E = (unsigned short*)(ws + off);   off += (size_t)MM * LL * BB * QQ * 2;  // 134 MB
    unsigned short* At = (unsigned short*)(ws + off);  off += (size_t)MM * QQ * QQ * 2;       // 2 MB
    float* Bem = (float*)(ws + off);                   off += (size_t)MM * QQ * SS * 4;
    float* pi = (float*)(ws + off);                    off += (size_t)MM * QQ * 4;
    float* Lrow = (float*)(ws + off);                  off += (size_t)MM * QQ * 4;
    unsigned short* ax = (unsigned short*)(ws + off);  off += (size_t)2 * NCLU * 16 * QQ * 2;
    float* psum = (float*)(ws + off);                  off += (size_t)2 * NCLU * 4 * 16 * 4;
    unsigned int* flags = (unsigned int*)(ws + off);   off += 256;

    if (ws_size < off) {  // clean failure instead of corruption
        hipMemsetAsync(d_out, 0, (size_t)out_size * sizeof(float), stream);
        return;
    }

    prep_small<<<dim3(MM * (QQ + 1)), dim3(64), 0, stream>>>(init_logits, em_logits, pi, Bem);
    prep_arow<<<dim3(MM * QQ), dim3(64), 0, stream>>>(A_logits, Lrow);
    prep_at<<<dim3(MM * 64), dim3(256), 0, stream>>>(A_logits, Lrow, At);
    prep_e<<<dim3(MM * BB * (LL / 16)), dim3(256), 0, stream>>>(inputs, Bem, E);
    hipMemsetAsync(flags, 0, 256, stream);
    hmm_scan<<<dim3(64), dim3(256), 0, stream>>>(E, At, pi, ax, psum, flags, out);
}

// Round 3
// 1428.213 us; speedup vs baseline: 3.3019x; 3.3019x over previous
//
#include <hip/hip_runtime.h>
#include <hip/hip_bf16.h>
#include <math.h>

// Profile-HMM forward (scaled). M=4, B=64, L=512, Q=512, S=26.
//
// Round 3 (= round 2 + compile fix): single-WG-per-cluster scan. 16 clusters =
// (m, 16-batch group), each one workgroup of 1024 threads (16 waves) on one CU.
// A[m] quantized to fp8 e4m3 (x256 scale) and held entirely in VGPRs (64/wave);
// alpha quantized to fp8 each step, exchanged through LDS with a K-permuted
// layout so MFMA A-frags are contiguous b128 reads. No inter-WG traffic, no
// fences: two __syncthreads per step. E stays bf16; e-multiply + scaling fp32.
// loglik = sum log s_t, tracked per-stream in wave 0.

#define MM 4
#define BB 64
#define LL 512
#define QQ 512
#define SS 26
#define ASTR 528   // albuf row stride (bytes): 16-aligned, 2-way-max banks

typedef float f32x4 __attribute__((ext_vector_type(4)));
typedef unsigned long long u64_t;
typedef u64_t u64x2 __attribute__((ext_vector_type(2)));

__device__ __forceinline__ float bf2f(unsigned short u) {
    return __uint_as_float(((unsigned)u) << 16);
}
__device__ __forceinline__ unsigned short f2bf(float f) {
    unsigned u = __float_as_uint(f);
    u = u + 0x7FFFu + ((u >> 16) & 1u);   // RNE
    return (unsigned short)(u >> 16);
}
__device__ __forceinline__ unsigned char f2fp8(float x) {
    int r = __builtin_amdgcn_cvt_pk_fp8_f32(x, x, 0, false);
    return (unsigned char)(r & 0xFF);
}
// DPP row_shr accumulate: after shifts 1,2,4,8 lane 15 of each 16-row holds sum.
template<int SH>
__device__ __forceinline__ float dpp_shr_add(float x) {
    int t = __builtin_amdgcn_update_dpp(0, __float_as_int(x),
                                        0x110 | SH, 0xF, 0xF, false);
    return x + __int_as_float(t);
}
__device__ __forceinline__ float row_sum16(float x) {
    x = dpp_shr_add<1>(x);
    x = dpp_shr_add<2>(x);
    x = dpp_shr_add<4>(x);
    x = dpp_shr_add<8>(x);
    return x;
}

// ---------------- preproc ----------------

// grid MM*(QQ+1), block 64. r<QQ: Bem row softmax over S; r==QQ: pi softmax over Q.
__global__ void prep_small(const float* __restrict__ il, const float* __restrict__ em,
                           float* __restrict__ pi, float* __restrict__ Bem) {
    int blk = blockIdx.x;
    int m = blk / (QQ + 1);
    int r = blk % (QQ + 1);
    int lane = threadIdx.x;
    if (r < QQ) {
        float x = (lane < SS) ? em[((size_t)m * QQ + r) * SS + lane] : -1e30f;
        float mx = x;
        #pragma unroll
        for (int o = 1; o < 64; o <<= 1) mx = fmaxf(mx, __shfl_xor(mx, o));
        float e = (lane < SS) ? __expf(x - mx) : 0.f;
        float s = e;
        #pragma unroll
        for (int o = 1; o < 64; o <<= 1) s += __shfl_xor(s, o);
        if (lane < SS) Bem[((size_t)m * QQ + r) * SS + lane] = e / s;
    } else {
        float v[8];
        float mx = -1e30f;
        #pragma unroll
        for (int k = 0; k < 8; ++k) { v[k] = il[m * QQ + k * 64 + lane]; mx = fmaxf(mx, v[k]); }
        #pragma unroll
        for (int o = 1; o < 64; o <<= 1) mx = fmaxf(mx, __shfl_xor(mx, o));
        float s = 0.f;
        #pragma unroll
        for (int k = 0; k < 8; ++k) { v[k] = __expf(v[k] - mx); s += v[k]; }
        #pragma unroll
        for (int o = 1; o < 64; o <<= 1) s += __shfl_xor(s, o);
        #pragma unroll
        for (int k = 0; k < 8; ++k) pi[m * QQ + k * 64 + lane] = v[k] / s;
    }
}

// grid MM*QQ, block 64: per A row (m,q): Lrow = max + log(sum exp).
__global__ void prep_arow(const float* __restrict__ Al, float* __restrict__ Lrow) {
    int row = blockIdx.x;
    int lane = threadIdx.x;
    const float* p = Al + (size_t)row * QQ;
    float v[8];
    float mx = -1e30f;
    #pragma unroll
    for (int k = 0; k < 8; ++k) { v[k] = p[k * 64 + lane]; mx = fmaxf(mx, v[k]); }
    #pragma unroll
    for (int o = 1; o < 64; o <<= 1) mx = fmaxf(mx, __shfl_xor(mx, o));
    float s = 0.f;
    #pragma unroll
    for (int k = 0; k < 8; ++k) s += __expf(v[k] - mx);
    #pragma unroll
    for (int o = 1; o < 64; o <<= 1) s += __shfl_xor(s, o);
    if (lane == 0) Lrow[row] = mx + __logf(s);
}

// grid MM*8 (m, p-block of 64), block 256.
// Atq[m][p][pos(q)] = fp8(256 * softmax_over_p(A_logits[m][q][:])[p])
// pos(q): kt=q>>5, qd=(q>>3)&3, j=q&7 -> (kt>>1)*64 + qd*16 + (kt&1)*8 + j,
// so an MFMA B/A fragment (k = kt*32 + qd*8 + j) is 8 contiguous bytes and a
// b128 read covers the k-tile pair (2c, 2c+1).
__global__ void prep_atq(const float* __restrict__ Al, const float* __restrict__ Lrow,
                         unsigned char* __restrict__ Atq) {
    int bid = blockIdx.x;
    int m = bid >> 3, pb = bid & 7;
    __shared__ unsigned char tile[64][68];
    int l6 = threadIdx.x & 63, g = threadIdx.x >> 6;
    for (int c = 0; c < 8; ++c) {
        #pragma unroll
        for (int r = 0; r < 16; ++r) {
            int ql = g * 16 + r;
            int q = c * 64 + ql;
            float x = Al[((size_t)m * QQ + q) * QQ + pb * 64 + l6];
            tile[ql][l6] = f2fp8(__expf(x - Lrow[m * QQ + q]) * 256.f);
        }
        __syncthreads();
        #pragma unroll
        for (int r = 0; r < 16; ++r) {
            int pr = g * 16 + r;
            int half = (l6 >> 3) & 1, qd = l6 >> 4, j = l6 & 7;
            int ql = half * 32 + qd * 8 + j;   // inverse of pos within the 64-chunk
            Atq[((size_t)m * QQ + pb * 64 + pr) * QQ + c * 64 + l6] = tile[ql][pr];
        }
        __syncthreads();
    }
}

// grid MM*BB*8 (m, b, 64-t chunk), block 256, 2 q per thread, Bem in registers.
__global__ void prep_e(const float* __restrict__ inp, const float* __restrict__ Bem,
                       unsigned short* __restrict__ E) {
    int bid = blockIdx.x;
    int tc = bid & 7;
    int b = (bid >> 3) & 63;
    int m = bid >> 9;
    int q0 = threadIdx.x;                   // handles q0 and q0+256
    float bem0[SS], bem1[SS];
    const float* bp = Bem + (size_t)m * QQ * SS;
    #pragma unroll
    for (int j = 0; j < SS; ++j) bem0[j] = bp[(size_t)q0 * SS + j];
    #pragma unroll
    for (int j = 0; j < SS; ++j) bem1[j] = bp[(size_t)(q0 + 256) * SS + j];
    const float* ip = inp + (((size_t)(m * BB + b)) * LL + tc * 64) * SS;
    for (int lt = 0; lt < 64; ++lt) {
        int t = tc * 64 + lt;
        float a0 = 0.f, a1 = 0.f;
        #pragma unroll
        for (int j = 0; j < SS; ++j) {
            float x = ip[lt * SS + j];       // block-uniform -> scalar/broadcast load
            a0 += x * bem0[j];
            a1 += x * bem1[j];
        }
        size_t o = (((size_t)m * LL + t) * BB + b) * QQ + q0;
        E[o] = f2bf(a0);
        E[o + 256] = f2bf(a1);
    }
}

// ---------------- scan ----------------

__launch_bounds__(1024, 4)
__global__ void hmm_scan(const unsigned short* __restrict__ E,
                         const unsigned char* __restrict__ Atq,
                         const float* __restrict__ pi,
                         float* __restrict__ out) {
    const int c = blockIdx.x;               // 16 clusters
    const int m = c >> 2, bg = c & 3;
    const int tid = threadIdx.x;
    const int lane = tid & 63;
    const int wv = tid >> 6;                // 0..15
    const int n16 = lane & 15;
    const int quad = lane >> 4;

    __shared__ unsigned char albuf[16 * ASTR];  // [stream s][pos(q)] fp8
    __shared__ float psl[16][16];               // [s][wave] partial sums

    // Persistent B-fragments: this wave's 32 columns of fp8(256*A[m]), full K.
    // 32 x u64 = 64 VGPRs.
    u64_t breg[2][16];
    {
        const unsigned char* Ab = Atq + (size_t)m * QQ * QQ;
        #pragma unroll
        for (int h = 0; h < 2; ++h) {
            int p = wv * 32 + h * 16 + n16;
            const unsigned char* rp = Ab + (size_t)p * QQ + quad * 16;
            #pragma unroll
            for (int kt = 0; kt < 16; ++kt)
                breg[h][kt] = *(const u64_t*)(rp + (kt >> 1) * 64 + (kt & 1) * 8);
        }
    }

    // LDS byte positions for this lane's two alpha columns (permuted layout)
    int posw[2];
    #pragma unroll
    for (int h = 0; h < 2; ++h) {
        int pp = wv * 32 + h * 16 + n16;
        int ktp = pp >> 5, qdp = (pp >> 3) & 3, jp = pp & 7;
        posw[h] = (ktp >> 1) * 64 + qdp * 16 + (ktp & 1) * 8 + jp;
    }

    // ---- t = 0: v = 65536 * pi * e0 (fp32)
    float v[2][4];
    #pragma unroll
    for (int h = 0; h < 2; ++h) {
        int p = wv * 32 + h * 16 + n16;
        float pv = pi[m * QQ + p] * 65536.f;
        #pragma unroll
        for (int i = 0; i < 4; ++i) {
            int b = bg * 16 + quad * 4 + i;
            v[h][i] = pv * bf2f(E[(((size_t)m * LL) * BB + b) * QQ + p]);
        }
    }
    #pragma unroll
    for (int i = 0; i < 4; ++i) {
        float ps = row_sum16(v[0][i] + v[1][i]);
        if (n16 == 15) psl[quad * 4 + i][wv] = ps;
    }

    float ll = 0.f;
    const float LOG64K = 11.090354888959125f;   // log(65536)

    for (int t = 0; ; ++t) {
        __syncthreads();                        // psl_t complete
        // S_t per stream (every lane computes S[n16]; S_t = 65536 * s_t)
        f32x4 sv = *(const f32x4*)&psl[n16][0];
        sv += *(const f32x4*)&psl[n16][4];
        sv += *(const f32x4*)&psl[n16][8];
        sv += *(const f32x4*)&psl[n16][12];
        float S = sv[0] + sv[1] + sv[2] + sv[3];
        if (wv == 0 && lane < 16) ll += __logf(S) - LOG64K;
        if (t == LL - 1) break;

        float inv[4];
        #pragma unroll
        for (int i = 0; i < 4; ++i) inv[i] = 256.f / __shfl(S, quad * 4 + i);

        // store alpha_hat_t = fp8(256 * a_t / s_t) into permuted LDS layout
        #pragma unroll
        for (int h = 0; h < 2; ++h)
            #pragma unroll
            for (int i = 0; i < 4; ++i)
                albuf[(quad * 4 + i) * ASTR + posw[h]] = f2fp8(v[h][i] * inv[i]);

        // prefetch e_{t+1} (independent of scan state; hidden by barrier+MFMA)
        unsigned short eu[2][4];
        #pragma unroll
        for (int h = 0; h < 2; ++h) {
            int p = wv * 32 + h * 16 + n16;
            #pragma unroll
            for (int i = 0; i < 4; ++i) {
                int b = bg * 16 + quad * 4 + i;
                eu[h][i] = E[(((size_t)m * LL + (t + 1)) * BB + b) * QQ + p];
            }
        }
        __syncthreads();                        // albuf ready

        // r = alpha_hat @ A_hat : 32 fp8 MFMA, 4 independent chains
        f32x4 a00 = {0.f,0.f,0.f,0.f}, a01 = {0.f,0.f,0.f,0.f};
        f32x4 a10 = {0.f,0.f,0.f,0.f}, a11 = {0.f,0.f,0.f,0.f};
        const unsigned char* ar = albuf + n16 * ASTR + quad * 16;
        #pragma unroll
        for (int cc = 0; cc < 8; ++cc) {
            u64x2 af = *(const u64x2*)(ar + cc * 64);   // b128: k-tiles 2cc, 2cc+1
            a00 = __builtin_amdgcn_mfma_f32_16x16x32_fp8_fp8(
                      (long long)af.x, (long long)breg[0][2*cc],   a00, 0, 0, 0);
            a10 = __builtin_amdgcn_mfma_f32_16x16x32_fp8_fp8(
                      (long long)af.x, (long long)breg[1][2*cc],   a10, 0, 0, 0);
            a01 = __builtin_amdgcn_mfma_f32_16x16x32_fp8_fp8(
                      (long long)af.y, (long long)breg[0][2*cc+1], a01, 0, 0, 0);
            a11 = __builtin_amdgcn_mfma_f32_16x16x32_fp8_fp8(
                      (long long)af.y, (long long)breg[1][2*cc+1], a11, 0, 0, 0);
        }
        // v_{t+1} = 65536 * a_{t+1} = acc * e_{t+1}   (acc = 65536 * r)
        #pragma unroll
        for (int i = 0; i < 4; ++i) {
            v[0][i] = (a00[i] + a01[i]) * bf2f(eu[0][i]);
            v[1][i] = (a10[i] + a11[i]) * bf2f(eu[1][i]);
        }
        #pragma unroll
        for (int i = 0; i < 4; ++i) {
            float ps = row_sum16(v[0][i] + v[1][i]);
            if (n16 == 15) psl[quad * 4 + i][wv] = ps;
        }
    }

    if (wv == 0 && lane < 16)
        out[m * BB + bg * 16 + lane] = ll;
}

// ---------------- host ----------------

extern "C" void kernel_launch(void* const* d_in, const int* in_sizes, int n_in,
                              void* d_out, int out_size, void* d_ws, size_t ws_size,
                              hipStream_t stream) {
    const float* inputs = (const float*)d_in[0];
    const float* A_logits = (const float*)d_in[1];
    const float* init_logits = (const float*)d_in[2];
    const float* em_logits = (const float*)d_in[3];
    float* out = (float*)d_out;

    char* ws = (char*)d_ws;
    size_t off = 0;
    unsigned short* E = (unsigned short*)(ws + off);  off += (size_t)MM * LL * BB * QQ * 2;  // 134 MB
    unsigned char* Atq = (unsigned char*)(ws + off);  off += (size_t)MM * QQ * QQ;           // 1 MB
    float* Bem = (float*)(ws + off);                  off += (size_t)MM * QQ * SS * 4;
    float* pi = (float*)(ws + off);                   off += (size_t)MM * QQ * 4;
    float* Lrow = (float*)(ws + off);                 off += (size_t)MM * QQ * 4;

    if (ws_size < off) {
        (void)hipMemsetAsync(d_out, 0, (size_t)out_size * sizeof(float), stream);
        return;
    }

    prep_small<<<dim3(MM * (QQ + 1)), dim3(64), 0, stream>>>(init_logits, em_logits, pi, Bem);
    prep_arow<<<dim3(MM * QQ), dim3(64), 0, stream>>>(A_logits, Lrow);
    prep_atq<<<dim3(MM * 8), dim3(256), 0, stream>>>(A_logits, Lrow, Atq);
    prep_e<<<dim3(MM * BB * 8), dim3(256), 0, stream>>>(inputs, Bem, E);
    hmm_scan<<<dim3(16), dim3(1024), 0, stream>>>(E, Atq, pi, out);
}

// Round 4
// 872.041 us; speedup vs baseline: 5.4077x; 1.6378x over previous
//
#include <hip/hip_runtime.h>
#include <hip/hip_bf16.h>
#include <math.h>

// Profile-HMM forward (scaled). M=4, B=64, L=512, Q=512, S=26.
//
// Round 4: single-WG-per-cluster scan, 16 clusters x 512 threads (8 waves,
// 64 p-cols/wave, A[m] fp8 in VGPRs).  ONE barrier per step: albuf is scaled
// by a KNOWN per-step gain g_t = 128/lambda_t (lambda from previous step), so
// alpha-exchange + partial-sum writes precede a single __syncthreads.
// Loglik is exact: ll = log S_511 - sum_t log(256*g_t)  (telescoping product;
// lambda only controls fp8 dynamic range, no feedback).
// MFMA output is transposed in-register (2 DPP stages) so each lane owns
// (one stream s, 4 consecutive p): e-loads = coalesced b64, albuf stores =
// packed ds_write_b32 (~2-way banks), psum = 2 shfl_xor.

#define MM 4
#define BB 64
#define LL 512
#define QQ 512
#define SS 26
#define ASTR 528   // albuf row stride bytes (16-mult)

typedef float f32x4 __attribute__((ext_vector_type(4)));
typedef unsigned long long u64_t;
typedef u64_t u64x2 __attribute__((ext_vector_type(2)));

__device__ __forceinline__ float bf2f(unsigned short u) {
    return __uint_as_float(((unsigned)u) << 16);
}
__device__ __forceinline__ unsigned short f2bf(float f) {
    unsigned u = __float_as_uint(f);
    u = u + 0x7FFFu + ((u >> 16) & 1u);   // RNE
    return (unsigned short)(u >> 16);
}
__device__ __forceinline__ unsigned char f2fp8(float x) {
    int r = __builtin_amdgcn_cvt_pk_fp8_f32(x, x, 0, false);
    return (unsigned char)(r & 0xFF);
}
template<int CTRL>
__device__ __forceinline__ float qperm(float x) {
    return __int_as_float(__builtin_amdgcn_update_dpp(
        0, __float_as_int(x), CTRL, 0xF, 0xF, false));
}
// 4x4 f32 transpose across lanes (low 2 lane bits) x regs r[0..3].
// In: r[i] = M[row i][col = lane&3]. Out: r[j] = M[row lane&3][col j].
__device__ __forceinline__ void tr4(float r[4], bool odd, bool bit1) {
    float t0 = qperm<0xB1>(r[0]), t1 = qperm<0xB1>(r[1]);
    float t2 = qperm<0xB1>(r[2]), t3 = qperm<0xB1>(r[3]);
    float n0 = odd ? t1 : r[0];
    float n1 = odd ? r[1] : t0;
    float n2 = odd ? t3 : r[2];
    float n3 = odd ? r[3] : t2;
    float u0 = qperm<0x4E>(n0), u1 = qperm<0x4E>(n1);
    float u2 = qperm<0x4E>(n2), u3 = qperm<0x4E>(n3);
    r[0] = bit1 ? u2 : n0;
    r[1] = bit1 ? u3 : n1;
    r[2] = bit1 ? n2 : u0;
    r[3] = bit1 ? n3 : u1;
}

// ---------------- preproc (unchanged from round 3) ----------------

__global__ void prep_small(const float* __restrict__ il, const float* __restrict__ em,
                           float* __restrict__ pi, float* __restrict__ Bem) {
    int blk = blockIdx.x;
    int m = blk / (QQ + 1);
    int r = blk % (QQ + 1);
    int lane = threadIdx.x;
    if (r < QQ) {
        float x = (lane < SS) ? em[((size_t)m * QQ + r) * SS + lane] : -1e30f;
        float mx = x;
        #pragma unroll
        for (int o = 1; o < 64; o <<= 1) mx = fmaxf(mx, __shfl_xor(mx, o));
        float e = (lane < SS) ? __expf(x - mx) : 0.f;
        float s = e;
        #pragma unroll
        for (int o = 1; o < 64; o <<= 1) s += __shfl_xor(s, o);
        if (lane < SS) Bem[((size_t)m * QQ + r) * SS + lane] = e / s;
    } else {
        float v[8];
        float mx = -1e30f;
        #pragma unroll
        for (int k = 0; k < 8; ++k) { v[k] = il[m * QQ + k * 64 + lane]; mx = fmaxf(mx, v[k]); }
        #pragma unroll
        for (int o = 1; o < 64; o <<= 1) mx = fmaxf(mx, __shfl_xor(mx, o));
        float s = 0.f;
        #pragma unroll
        for (int k = 0; k < 8; ++k) { v[k] = __expf(v[k] - mx); s += v[k]; }
        #pragma unroll
        for (int o = 1; o < 64; o <<= 1) s += __shfl_xor(s, o);
        #pragma unroll
        for (int k = 0; k < 8; ++k) pi[m * QQ + k * 64 + lane] = v[k] / s;
    }
}

__global__ void prep_arow(const float* __restrict__ Al, float* __restrict__ Lrow) {
    int row = blockIdx.x;
    int lane = threadIdx.x;
    const float* p = Al + (size_t)row * QQ;
    float v[8];
    float mx = -1e30f;
    #pragma unroll
    for (int k = 0; k < 8; ++k) { v[k] = p[k * 64 + lane]; mx = fmaxf(mx, v[k]); }
    #pragma unroll
    for (int o = 1; o < 64; o <<= 1) mx = fmaxf(mx, __shfl_xor(mx, o));
    float s = 0.f;
    #pragma unroll
    for (int k = 0; k < 8; ++k) s += __expf(v[k] - mx);
    #pragma unroll
    for (int o = 1; o < 64; o <<= 1) s += __shfl_xor(s, o);
    if (lane == 0) Lrow[row] = mx + __logf(s);
}

// Atq[m][p][pos(q)] = fp8(256*softmax_p(A_logits[m][q][:])[p]);
// pos(q): kt=q>>5, qd=(q>>3)&3, j=q&7 -> (kt>>1)*64 + qd*16 + (kt&1)*8 + j.
__global__ void prep_atq(const float* __restrict__ Al, const float* __restrict__ Lrow,
                         unsigned char* __restrict__ Atq) {
    int bid = blockIdx.x;
    int m = bid >> 3, pb = bid & 7;
    __shared__ unsigned char tile[64][68];
    int l6 = threadIdx.x & 63, g = threadIdx.x >> 6;
    for (int c = 0; c < 8; ++c) {
        #pragma unroll
        for (int r = 0; r < 16; ++r) {
            int ql = g * 16 + r;
            int q = c * 64 + ql;
            float x = Al[((size_t)m * QQ + q) * QQ + pb * 64 + l6];
            tile[ql][l6] = f2fp8(__expf(x - Lrow[m * QQ + q]) * 256.f);
        }
        __syncthreads();
        #pragma unroll
        for (int r = 0; r < 16; ++r) {
            int pr = g * 16 + r;
            int half = (l6 >> 3) & 1, qd = l6 >> 4, j = l6 & 7;
            int ql = half * 32 + qd * 8 + j;
            Atq[((size_t)m * QQ + pb * 64 + pr) * QQ + c * 64 + l6] = tile[ql][pr];
        }
        __syncthreads();
    }
}

__global__ void prep_e(const float* __restrict__ inp, const float* __restrict__ Bem,
                       unsigned short* __restrict__ E) {
    int bid = blockIdx.x;
    int tc = bid & 7;
    int b = (bid >> 3) & 63;
    int m = bid >> 9;
    int q0 = threadIdx.x;
    float bem0[SS], bem1[SS];
    const float* bp = Bem + (size_t)m * QQ * SS;
    #pragma unroll
    for (int j = 0; j < SS; ++j) bem0[j] = bp[(size_t)q0 * SS + j];
    #pragma unroll
    for (int j = 0; j < SS; ++j) bem1[j] = bp[(size_t)(q0 + 256) * SS + j];
    const float* ip = inp + (((size_t)(m * BB + b)) * LL + tc * 64) * SS;
    for (int lt = 0; lt < 64; ++lt) {
        int t = tc * 64 + lt;
        float a0 = 0.f, a1 = 0.f;
        #pragma unroll
        for (int j = 0; j < SS; ++j) {
            float x = ip[lt * SS + j];
            a0 += x * bem0[j];
            a1 += x * bem1[j];
        }
        size_t o = (((size_t)m * LL + t) * BB + b) * QQ + q0;
        E[o] = f2bf(a0);
        E[o + 256] = f2bf(a1);
    }
}

// ---------------- scan ----------------

__launch_bounds__(512, 2)
__global__ void hmm_scan(const unsigned short* __restrict__ E,
                         const unsigned char* __restrict__ Atq,
                         const float* __restrict__ pi,
                         float* __restrict__ out) {
    const int c = blockIdx.x;               // 16 clusters
    const int m = c >> 2, bg = c & 3;
    const int tid = threadIdx.x;
    const int lane = tid & 63;
    const int wv = tid >> 6;                // 0..7
    const int n16 = lane & 15;
    const int quad = lane >> 4;
    const int sl = quad * 4 + (lane & 3);   // this lane's stream (post-transpose)
    const int kk = (lane >> 2) & 3;         // p-subgroup within 16-tile
    const bool odd = (lane & 1) != 0;
    const bool bit1 = (lane & 2) != 0;
    const float LOG256 = 5.545177444479562f;

    __shared__ unsigned char albuf[2][16 * ASTR];   // [parity][s][pos(q)] fp8
    __shared__ float psl[2][16][12];                // [parity][s][wave] (padded)

    // persistent B-fragments: this wave's 64 p-columns of fp8(256*A[m]), full K.
    u64_t breg[4][16];
    {
        const unsigned char* Ab = Atq + (size_t)m * QQ * QQ;
        #pragma unroll
        for (int h = 0; h < 4; ++h) {
            int p = wv * 64 + h * 16 + n16;
            const unsigned char* rp = Ab + (size_t)p * QQ + quad * 16;
            #pragma unroll
            for (int kt = 0; kt < 16; ++kt)
                breg[h][kt] = *(const u64_t*)(rp + (kt >> 1) * 64 + (kt & 1) * 8);
        }
    }

    // albuf write offsets: row sl, b32 covering p = wv*64+h*16+kk*4 .. +3
    int wq[4];
    #pragma unroll
    for (int h = 0; h < 4; ++h) {
        int qdp = (2 * h + (kk >> 1)) & 3;
        wq[h] = sl * ASTR + wv * 64 + qdp * 16 + (h >> 1) * 8 + (kk & 1) * 4;
    }
    const unsigned char* arb = &albuf[0][0] + n16 * ASTR + quad * 16;

    const int b = bg * 16 + sl;
    const size_t ebase = (size_t)m * LL * BB * QQ;

    float v[4][4];
    ushort4 ea[4], eb[4];

    // prologue: prefetch e_1 -> ea ; v_0 = pi * e_0 (lambda_0 = 1)
    {
        const ushort4* E1 = (const ushort4*)(E + ebase + (size_t)1 * BB * QQ + (size_t)b * QQ);
        #pragma unroll
        for (int h = 0; h < 4; ++h) ea[h] = E1[(wv * 64 + h * 16 + kk * 4) >> 2];
        #pragma unroll
        for (int h = 0; h < 4; ++h) {
            int p0 = wv * 64 + h * 16 + kk * 4;
            f32x4 pv = *(const f32x4*)(pi + m * QQ + p0);
            ushort4 e0 = *(const ushort4*)(E + ebase + (size_t)b * QQ + p0);
            v[h][0] = pv[0] * bf2f(e0.x);
            v[h][1] = pv[1] * bf2f(e0.y);
            v[h][2] = pv[2] * bf2f(e0.z);
            v[h][3] = pv[3] * bf2f(e0.w);
        }
    }

    float lam = 1.0f;
    float ll = 0.0f;

    auto body = [&](int t, ushort4 (&ecur)[4], ushort4 (&enxt)[4]) {
        const int par = t & 1;
        // prefetch e_{t+2} (consumed next iteration)
        int tp = t + 2; if (tp > LL - 1) tp = LL - 1;
        const ushort4* Ep = (const ushort4*)(E + ebase + (size_t)tp * BB * QQ + (size_t)b * QQ);
        #pragma unroll
        for (int h = 0; h < 4; ++h) enxt[h] = Ep[(wv * 64 + h * 16 + kk * 4) >> 2];

        float g = 128.0f * __builtin_amdgcn_rcpf(lam);
        // alpha-hat_t = fp8(g * v_t), packed 4 bytes -> one b32 per h
        unsigned char* ab = &albuf[par][0];
        #pragma unroll
        for (int h = 0; h < 4; ++h) {
            int d = __builtin_amdgcn_cvt_pk_fp8_f32(g * v[h][0], g * v[h][1], 0, false);
            d = __builtin_amdgcn_cvt_pk_fp8_f32(g * v[h][2], g * v[h][3], d, true);
            *(int*)(ab + wq[h]) = d;
        }
        // partial sum for S_t (own stream sl)
        float ps = 0.f;
        #pragma unroll
        for (int h = 0; h < 4; ++h) ps += (v[h][0] + v[h][1]) + (v[h][2] + v[h][3]);
        ps += __shfl_xor(ps, 4);
        ps += __shfl_xor(ps, 8);
        if ((lane & 12) == 0) psl[par][sl][wv] = ps;

        ll -= __logf(g) + LOG256;   // exact: ll = log S_L - sum log(256 g_t)

        __syncthreads();

        // S_t -> lambda_{t+1} (range control only)
        const f32x4* pr = (const f32x4*)&psl[par][sl][0];
        f32x4 s0 = pr[0], s1 = pr[1];
        float S = ((s0[0] + s0[1]) + (s0[2] + s0[3])) + ((s1[0] + s1[1]) + (s1[2] + s1[3]));
        lam = 256.0f * g * S;

        // r = alpha-hat @ A-hat : 64 fp8 MFMA, 8 independent chains
        f32x4 acc[4][2];
        #pragma unroll
        for (int h = 0; h < 4; ++h) {
            acc[h][0] = (f32x4){0.f, 0.f, 0.f, 0.f};
            acc[h][1] = (f32x4){0.f, 0.f, 0.f, 0.f};
        }
        const unsigned char* ar = arb + par * (16 * ASTR);
        #pragma unroll
        for (int cc = 0; cc < 8; ++cc) {
            u64x2 af = *(const u64x2*)(ar + cc * 64);
            #pragma unroll
            for (int h = 0; h < 4; ++h) {
                acc[h][0] = __builtin_amdgcn_mfma_f32_16x16x32_fp8_fp8(
                    (long long)af.x, (long long)breg[h][2 * cc], acc[h][0], 0, 0, 0);
                acc[h][1] = __builtin_amdgcn_mfma_f32_16x16x32_fp8_fp8(
                    (long long)af.y, (long long)breg[h][2 * cc + 1], acc[h][1], 0, 0, 0);
            }
        }
        // transpose to (one s, 4 consecutive p) ownership, then e-multiply
        #pragma unroll
        for (int h = 0; h < 4; ++h) {
            float r[4];
            #pragma unroll
            for (int j = 0; j < 4; ++j) r[j] = acc[h][0][j] + acc[h][1][j];
            tr4(r, odd, bit1);
            v[h][0] = r[0] * bf2f(ecur[h].x);
            v[h][1] = r[1] * bf2f(ecur[h].y);
            v[h][2] = r[2] * bf2f(ecur[h].z);
            v[h][3] = r[3] * bf2f(ecur[h].w);
        }
    };

    for (int t = 0; t < LL - 2; t += 2) { body(t, ea, eb); body(t + 1, eb, ea); }
    body(LL - 2, ea, eb);

    // epilogue: S_511
    {
        float ps = 0.f;
        #pragma unroll
        for (int h = 0; h < 4; ++h) ps += (v[h][0] + v[h][1]) + (v[h][2] + v[h][3]);
        ps += __shfl_xor(ps, 4);
        ps += __shfl_xor(ps, 8);
        if ((lane & 12) == 0) psl[1][sl][wv] = ps;
        __syncthreads();
        const f32x4* pr = (const f32x4*)&psl[1][sl][0];
        f32x4 s0 = pr[0], s1 = pr[1];
        float S = ((s0[0] + s0[1]) + (s0[2] + s0[3])) + ((s1[0] + s1[1]) + (s1[2] + s1[3]));
        ll += __logf(S);
        if (wv == 0 && (lane & 12) == 0)
            out[m * BB + bg * 16 + sl] = ll;
    }
}

// ---------------- host ----------------

extern "C" void kernel_launch(void* const* d_in, const int* in_sizes, int n_in,
                              void* d_out, int out_size, void* d_ws, size_t ws_size,
                              hipStream_t stream) {
    const float* inputs = (const float*)d_in[0];
    const float* A_logits = (const float*)d_in[1];
    const float* init_logits = (const float*)d_in[2];
    const float* em_logits = (const float*)d_in[3];
    float* out = (float*)d_out;

    char* ws = (char*)d_ws;
    size_t off = 0;
    unsigned short* E = (unsigned short*)(ws + off);  off += (size_t)MM * LL * BB * QQ * 2;  // 134 MB
    unsigned char* Atq = (unsigned char*)(ws + off);  off += (size_t)MM * QQ * QQ;           // 1 MB
    float* Bem = (float*)(ws + off);                  off += (size_t)MM * QQ * SS * 4;
    float* pi = (float*)(ws + off);                   off += (size_t)MM * QQ * 4;
    float* Lrow = (float*)(ws + off);                 off += (size_t)MM * QQ * 4;

    if (ws_size < off) {
        (void)hipMemsetAsync(d_out, 0, (size_t)out_size * sizeof(float), stream);
        return;
    }

    prep_small<<<dim3(MM * (QQ + 1)), dim3(64), 0, stream>>>(init_logits, em_logits, pi, Bem);
    prep_arow<<<dim3(MM * QQ), dim3(64), 0, stream>>>(A_logits, Lrow);
    prep_atq<<<dim3(MM * 8), dim3(256), 0, stream>>>(A_logits, Lrow, Atq);
    prep_e<<<dim3(MM * BB * 8), dim3(256), 0, stream>>>(inputs, Bem, E);
    hmm_scan<<<dim3(16), dim3(512), 0, stream>>>(E, Atq, pi, out);
}

// Round 5
// 760.152 us; speedup vs baseline: 6.2037x; 1.1472x over previous
//
#include <hip/hip_runtime.h>
#include <hip/hip_bf16.h>
#include <math.h>

// Profile-HMM forward (scaled). M=4, B=64, L=512, Q=512, S=26.
//
// Round 5: round-4 structure (16 clusters x 512 thr, one barrier/step,
// lag-scaled gain g_t, DPP 4x4 transpose, e ping-pong prefetch) with the scan
// MFMA switched to mfma_scale_f32_16x16x128_f8f6f4 (unit e8m0 scales = exact
// e4m3 math at ~2.3x the plain fp8 rate). K=128 per MFMA -> a lane's 32
// operand bytes are k=quad*32+j contiguous, so alpha/Atq layouts are natural
// order: A-frags = 2 adjacent ds_read_b128, breg = plain 32B global loads.

#define MM 4
#define BB 64
#define LL 512
#define QQ 512
#define SS 26
#define ASTR 528   // albuf row stride bytes (16-mult; rows 4 banks apart)

typedef float f32x4 __attribute__((ext_vector_type(4)));
typedef int i32x4 __attribute__((ext_vector_type(4)));
typedef int i32x8 __attribute__((ext_vector_type(8)));

__device__ __forceinline__ float bf2f(unsigned short u) {
    return __uint_as_float(((unsigned)u) << 16);
}
__device__ __forceinline__ unsigned short f2bf(float f) {
    unsigned u = __float_as_uint(f);
    u = u + 0x7FFFu + ((u >> 16) & 1u);   // RNE
    return (unsigned short)(u >> 16);
}
__device__ __forceinline__ unsigned char f2fp8(float x) {
    int r = __builtin_amdgcn_cvt_pk_fp8_f32(x, x, 0, false);
    return (unsigned char)(r & 0xFF);
}
template<int CTRL>
__device__ __forceinline__ float qperm(float x) {
    return __int_as_float(__builtin_amdgcn_update_dpp(
        0, __float_as_int(x), CTRL, 0xF, 0xF, false));
}
// 4x4 f32 transpose across lanes (low 2 lane bits) x regs r[0..3].
__device__ __forceinline__ void tr4(float r[4], bool odd, bool bit1) {
    float t0 = qperm<0xB1>(r[0]), t1 = qperm<0xB1>(r[1]);
    float t2 = qperm<0xB1>(r[2]), t3 = qperm<0xB1>(r[3]);
    float n0 = odd ? t1 : r[0];
    float n1 = odd ? r[1] : t0;
    float n2 = odd ? t3 : r[2];
    float n3 = odd ? r[3] : t2;
    float u0 = qperm<0x4E>(n0), u1 = qperm<0x4E>(n1);
    float u2 = qperm<0x4E>(n2), u3 = qperm<0x4E>(n3);
    r[0] = bit1 ? u2 : n0;
    r[1] = bit1 ? u3 : n1;
    r[2] = bit1 ? n2 : u0;
    r[3] = bit1 ? n3 : u1;
}
__device__ __forceinline__ i32x8 ld32B_lds(const unsigned char* p) {
    i32x4 lo = *(const i32x4*)p;
    i32x4 hi = *(const i32x4*)(p + 16);
    return __builtin_shufflevector(lo, hi, 0, 1, 2, 3, 4, 5, 6, 7);
}

// ---------------- preproc ----------------

__global__ void prep_small(const float* __restrict__ il, const float* __restrict__ em,
                           float* __restrict__ pi, float* __restrict__ Bem) {
    int blk = blockIdx.x;
    int m = blk / (QQ + 1);
    int r = blk % (QQ + 1);
    int lane = threadIdx.x;
    if (r < QQ) {
        float x = (lane < SS) ? em[((size_t)m * QQ + r) * SS + lane] : -1e30f;
        float mx = x;
        #pragma unroll
        for (int o = 1; o < 64; o <<= 1) mx = fmaxf(mx, __shfl_xor(mx, o));
        float e = (lane < SS) ? __expf(x - mx) : 0.f;
        float s = e;
        #pragma unroll
        for (int o = 1; o < 64; o <<= 1) s += __shfl_xor(s, o);
        if (lane < SS) Bem[((size_t)m * QQ + r) * SS + lane] = e / s;
    } else {
        float v[8];
        float mx = -1e30f;
        #pragma unroll
        for (int k = 0; k < 8; ++k) { v[k] = il[m * QQ + k * 64 + lane]; mx = fmaxf(mx, v[k]); }
        #pragma unroll
        for (int o = 1; o < 64; o <<= 1) mx = fmaxf(mx, __shfl_xor(mx, o));
        float s = 0.f;
        #pragma unroll
        for (int k = 0; k < 8; ++k) { v[k] = __expf(v[k] - mx); s += v[k]; }
        #pragma unroll
        for (int o = 1; o < 64; o <<= 1) s += __shfl_xor(s, o);
        #pragma unroll
        for (int k = 0; k < 8; ++k) pi[m * QQ + k * 64 + lane] = v[k] / s;
    }
}

__global__ void prep_arow(const float* __restrict__ Al, float* __restrict__ Lrow) {
    int row = blockIdx.x;
    int lane = threadIdx.x;
    const float* p = Al + (size_t)row * QQ;
    float v[8];
    float mx = -1e30f;
    #pragma unroll
    for (int k = 0; k < 8; ++k) { v[k] = p[k * 64 + lane]; mx = fmaxf(mx, v[k]); }
    #pragma unroll
    for (int o = 1; o < 64; o <<= 1) mx = fmaxf(mx, __shfl_xor(mx, o));
    float s = 0.f;
    #pragma unroll
    for (int k = 0; k < 8; ++k) s += __expf(v[k] - mx);
    #pragma unroll
    for (int o = 1; o < 64; o <<= 1) s += __shfl_xor(s, o);
    if (lane == 0) Lrow[row] = mx + __logf(s);
}

// Atq[m][p][q] = fp8(256 * softmax_over_p(A_logits[m][q][:])[p])  (natural q)
__global__ void prep_atq(const float* __restrict__ Al, const float* __restrict__ Lrow,
                         unsigned char* __restrict__ Atq) {
    int bid = blockIdx.x;
    int m = bid >> 3, pb = bid & 7;
    __shared__ unsigned char tile[64][68];
    int l6 = threadIdx.x & 63, g = threadIdx.x >> 6;
    for (int c = 0; c < 8; ++c) {
        #pragma unroll
        for (int r = 0; r < 16; ++r) {
            int ql = g * 16 + r;
            int q = c * 64 + ql;
            float x = Al[((size_t)m * QQ + q) * QQ + pb * 64 + l6];
            tile[ql][l6] = f2fp8(__expf(x - Lrow[m * QQ + q]) * 256.f);
        }
        __syncthreads();
        #pragma unroll
        for (int r = 0; r < 16; ++r) {
            int pr = g * 16 + r;
            Atq[((size_t)m * QQ + pb * 64 + pr) * QQ + c * 64 + l6] = tile[l6][pr];
        }
        __syncthreads();
    }
}

__global__ void prep_e(const float* __restrict__ inp, const float* __restrict__ Bem,
                       unsigned short* __restrict__ E) {
    int bid = blockIdx.x;
    int tc = bid & 7;
    int b = (bid >> 3) & 63;
    int m = bid >> 9;
    int q0 = threadIdx.x;
    float bem0[SS], bem1[SS];
    const float* bp = Bem + (size_t)m * QQ * SS;
    #pragma unroll
    for (int j = 0; j < SS; ++j) bem0[j] = bp[(size_t)q0 * SS + j];
    #pragma unroll
    for (int j = 0; j < SS; ++j) bem1[j] = bp[(size_t)(q0 + 256) * SS + j];
    const float* ip = inp + (((size_t)(m * BB + b)) * LL + tc * 64) * SS;
    for (int lt = 0; lt < 64; ++lt) {
        int t = tc * 64 + lt;
        float a0 = 0.f, a1 = 0.f;
        #pragma unroll
        for (int j = 0; j < SS; ++j) {
            float x = ip[lt * SS + j];
            a0 += x * bem0[j];
            a1 += x * bem1[j];
        }
        size_t o = (((size_t)m * LL + t) * BB + b) * QQ + q0;
        E[o] = f2bf(a0);
        E[o + 256] = f2bf(a1);
    }
}

// ---------------- scan ----------------

__launch_bounds__(512, 2)
__global__ void hmm_scan(const unsigned short* __restrict__ E,
                         const unsigned char* __restrict__ Atq,
                         const float* __restrict__ pi,
                         float* __restrict__ out) {
    const int c = blockIdx.x;               // 16 clusters
    const int m = c >> 2, bg = c & 3;
    const int tid = threadIdx.x;
    const int lane = tid & 63;
    const int wv = tid >> 6;                // 0..7
    const int n16 = lane & 15;
    const int quad = lane >> 4;
    const int sl = quad * 4 + (lane & 3);   // this lane's stream (post-transpose)
    const int kk = (lane >> 2) & 3;         // p-subgroup within 16-tile
    const bool odd = (lane & 1) != 0;
    const bool bit1 = (lane & 2) != 0;
    const float LOG256 = 5.545177444479562f;

    __shared__ unsigned char albuf[2][16 * ASTR];   // [parity][s][q] fp8, natural q
    __shared__ float psl[2][16][12];                // [parity][s][wave] (padded)

    // persistent B-fragments: this wave's 64 p-columns of fp8(256*A[m]).
    // breg[h][kc] = 32 bytes (k = kc*128 + quad*32 .. +31), 128 VGPRs total.
    i32x8 breg[4][4];
    {
        const unsigned char* Ab = Atq + (size_t)m * QQ * QQ;
        #pragma unroll
        for (int h = 0; h < 4; ++h) {
            int p = wv * 64 + h * 16 + n16;
            const unsigned char* rp = Ab + (size_t)p * QQ + quad * 32;
            #pragma unroll
            for (int kc = 0; kc < 4; ++kc)
                breg[h][kc] = ld32B_lds(rp + kc * 128);   // global path, same shuffle
        }
    }

    // albuf write offsets: row sl, b32 covering q = wv*64 + h*16 + kk*4 .. +3
    int wq[4];
    #pragma unroll
    for (int h = 0; h < 4; ++h)
        wq[h] = sl * ASTR + wv * 64 + h * 16 + kk * 4;

    const int b = bg * 16 + sl;
    const size_t ebase = (size_t)m * LL * BB * QQ;

    float v[4][4];
    ushort4 ea[4], eb[4];

    // prologue: prefetch e_1 -> ea ; v_0 = pi * e_0 (lambda_0 = 1)
    {
        const ushort4* E1 = (const ushort4*)(E + ebase + (size_t)1 * BB * QQ + (size_t)b * QQ);
        #pragma unroll
        for (int h = 0; h < 4; ++h) ea[h] = E1[(wv * 64 + h * 16 + kk * 4) >> 2];
        #pragma unroll
        for (int h = 0; h < 4; ++h) {
            int p0 = wv * 64 + h * 16 + kk * 4;
            f32x4 pv = *(const f32x4*)(pi + m * QQ + p0);
            ushort4 e0 = *(const ushort4*)(E + ebase + (size_t)b * QQ + p0);
            v[h][0] = pv[0] * bf2f(e0.x);
            v[h][1] = pv[1] * bf2f(e0.y);
            v[h][2] = pv[2] * bf2f(e0.z);
            v[h][3] = pv[3] * bf2f(e0.w);
        }
    }

    float lam = 1.0f;
    float ll = 0.0f;

    auto body = [&](int t, ushort4 (&ecur)[4], ushort4 (&enxt)[4]) {
        const int par = t & 1;
        // prefetch e_{t+2} (consumed next iteration)
        int tp = t + 2; if (tp > LL - 1) tp = LL - 1;
        const ushort4* Ep = (const ushort4*)(E + ebase + (size_t)tp * BB * QQ + (size_t)b * QQ);
        #pragma unroll
        for (int h = 0; h < 4; ++h) enxt[h] = Ep[(wv * 64 + h * 16 + kk * 4) >> 2];

        float g = 128.0f * __builtin_amdgcn_rcpf(lam);
        // alpha-hat_t = fp8(g * v_t), packed 4 bytes -> one b32 per h
        unsigned char* ab = &albuf[par][0];
        #pragma unroll
        for (int h = 0; h < 4; ++h) {
            int d = __builtin_amdgcn_cvt_pk_fp8_f32(g * v[h][0], g * v[h][1], 0, false);
            d = __builtin_amdgcn_cvt_pk_fp8_f32(g * v[h][2], g * v[h][3], d, true);
            *(int*)(ab + wq[h]) = d;
        }
        // partial sum for S_t (own stream sl)
        float ps = 0.f;
        #pragma unroll
        for (int h = 0; h < 4; ++h) ps += (v[h][0] + v[h][1]) + (v[h][2] + v[h][3]);
        ps += __shfl_xor(ps, 4);
        ps += __shfl_xor(ps, 8);
        if ((lane & 12) == 0) psl[par][sl][wv] = ps;

        ll -= __logf(g) + LOG256;   // exact: ll = log S_L - sum log(256 g_t)

        __syncthreads();

        // S_t -> lambda_{t+1} (range control only, off the MFMA critical path)
        const f32x4* pr = (const f32x4*)&psl[par][sl][0];
        f32x4 s0 = pr[0], s1 = pr[1];
        float S = ((s0[0] + s0[1]) + (s0[2] + s0[3])) + ((s1[0] + s1[1]) + (s1[2] + s1[3]));
        lam = 256.0f * g * S;

        // r = alpha-hat @ A-hat : 16 MX-fp8 MFMA (K=128), 4 independent chains
        f32x4 acc[4];
        #pragma unroll
        for (int h = 0; h < 4; ++h) acc[h] = (f32x4){0.f, 0.f, 0.f, 0.f};
        const unsigned char* ar = &albuf[par][0] + n16 * ASTR + quad * 32;
        #pragma unroll
        for (int kc = 0; kc < 4; ++kc) {
            i32x8 af = ld32B_lds(ar + kc * 128);
            #pragma unroll
            for (int h = 0; h < 4; ++h)
                acc[h] = __builtin_amdgcn_mfma_scale_f32_16x16x128_f8f6f4(
                    af, breg[h][kc], acc[h], 0, 0,
                    0, 0x7F7F7F7F, 0, 0x7F7F7F7F);   // unit e8m0 scales
        }
        // transpose to (one s, 4 consecutive p) ownership, then e-multiply
        #pragma unroll
        for (int h = 0; h < 4; ++h) {
            float r[4];
            #pragma unroll
            for (int j = 0; j < 4; ++j) r[j] = acc[h][j];
            tr4(r, odd, bit1);
            v[h][0] = r[0] * bf2f(ecur[h].x);
            v[h][1] = r[1] * bf2f(ecur[h].y);
            v[h][2] = r[2] * bf2f(ecur[h].z);
            v[h][3] = r[3] * bf2f(ecur[h].w);
        }
    };

    for (int t = 0; t < LL - 2; t += 2) { body(t, ea, eb); body(t + 1, eb, ea); }
    body(LL - 2, ea, eb);

    // epilogue: S_511
    {
        float ps = 0.f;
        #pragma unroll
        for (int h = 0; h < 4; ++h) ps += (v[h][0] + v[h][1]) + (v[h][2] + v[h][3]);
        ps += __shfl_xor(ps, 4);
        ps += __shfl_xor(ps, 8);
        if ((lane & 12) == 0) psl[1][sl][wv] = ps;
        __syncthreads();
        const f32x4* pr = (const f32x4*)&psl[1][sl][0];
        f32x4 s0 = pr[0], s1 = pr[1];
        float S = ((s0[0] + s0[1]) + (s0[2] + s0[3])) + ((s1[0] + s1[1]) + (s1[2] + s1[3]));
        ll += __logf(S);
        if (wv == 0 && (lane & 12) == 0)
            out[m * BB + bg * 16 + sl] = ll;
    }
}

// ---------------- host ----------------

extern "C" void kernel_launch(void* const* d_in, const int* in_sizes, int n_in,
                              void* d_out, int out_size, void* d_ws, size_t ws_size,
                              hipStream_t stream) {
    const float* inputs = (const float*)d_in[0];
    const float* A_logits = (const float*)d_in[1];
    const float* init_logits = (const float*)d_in[2];
    const float* em_logits = (const float*)d_in[3];
    float* out = (float*)d_out;

    char* ws = (char*)d_ws;
    size_t off = 0;
    unsigned short* E = (unsigned short*)(ws + off);  off += (size_t)MM * LL * BB * QQ * 2;  // 134 MB
    unsigned char* Atq = (unsigned char*)(ws + off);  off += (size_t)MM * QQ * QQ;           // 1 MB
    float* Bem = (float*)(ws + off);                  off += (size_t)MM * QQ * SS * 4;
    float* pi = (float*)(ws + off);                   off += (size_t)MM * QQ * 4;
    float* Lrow = (float*)(ws + off);                 off += (size_t)MM * QQ * 4;

    if (ws_size < off) {
        (void)hipMemsetAsync(d_out, 0, (size_t)out_size * sizeof(float), stream);
        return;
    }

    prep_small<<<dim3(MM * (QQ + 1)), dim3(64), 0, stream>>>(init_logits, em_logits, pi, Bem);
    prep_arow<<<dim3(MM * QQ), dim3(64), 0, stream>>>(A_logits, Lrow);
    prep_atq<<<dim3(MM * 8), dim3(256), 0, stream>>>(A_logits, Lrow, Atq);
    prep_e<<<dim3(MM * BB * 8), dim3(256), 0, stream>>>(inputs, Bem, E);
    hmm_scan<<<dim3(16), dim3(512), 0, stream>>>(E, Atq, pi, out);
}